// Round 1
// baseline (1945.309 us; speedup 1.0000x reference)
//
#include <hip/hip_runtime.h>

#define EPSV 1e-5f
#define SCALE 0.17677669529663687f  // 1/sqrt(32)

typedef unsigned short ushort_t;
typedef unsigned int uint_t;

__device__ __forceinline__ float u2f(uint_t x) { return __builtin_bit_cast(float, x); }
__device__ __forceinline__ uint_t f2u(float x) { return __builtin_bit_cast(uint_t, x); }
__device__ __forceinline__ float bflo(uint_t u) { return u2f(u << 16); }
__device__ __forceinline__ float bfhi(uint_t u) { return u2f(u & 0xFFFF0000u); }
__device__ __forceinline__ ushort_t f2bf(float f) {
    uint_t x = f2u(f);
    x += 0x7FFFu + ((x >> 16) & 1u);   // RNE
    return (ushort_t)(x >> 16);
}
__device__ __forceinline__ float wsum(float v) {
#pragma unroll
    for (int m = 32; m >= 1; m >>= 1) v += __shfl_xor(v, m, 64);
    return v;
}

// -------- K1: LayerNorm(m) -> mn (bf16) --------
__global__ __launch_bounds__(256) void k_ln_m(const float* __restrict__ m,
                                              const float* __restrict__ g,
                                              const float* __restrict__ b,
                                              ushort_t* __restrict__ mn) {
    const int lane = threadIdx.x & 63;
    const int row  = blockIdx.x * 4 + (threadIdx.x >> 6);
    const float4 x = *(const float4*)(m + (size_t)row * 256 + lane * 4);
    const float mu = wsum(x.x + x.y + x.z + x.w) * (1.f / 256.f);
    const float dx = x.x - mu, dy = x.y - mu, dz = x.z - mu, dw = x.w - mu;
    const float var = wsum(dx * dx + dy * dy + dz * dz + dw * dw) * (1.f / 256.f);
    const float rs = rsqrtf(var + EPSV);
    const float4 gg = *(const float4*)(g + lane * 4);
    const float4 bb = *(const float4*)(b + lane * 4);
    ushort4 o;
    o.x = f2bf(dx * rs * gg.x + bb.x);
    o.y = f2bf(dy * rs * gg.y + bb.y);
    o.z = f2bf(dz * rs * gg.z + bb.z);
    o.w = f2bf(dw * rs * gg.w + bb.w);
    *(ushort4*)(mn + (size_t)row * 256 + lane * 4) = o;
}

// -------- K2: LayerNorm(z) @ Wb -> pb[h][i][j] (f32) --------
__global__ __launch_bounds__(256) void k_pair_bias(const float* __restrict__ z,
                                                   const float* __restrict__ g,
                                                   const float* __restrict__ b,
                                                   const float* __restrict__ Wb,
                                                   float* __restrict__ pb) {
    const int lane = threadIdx.x & 63;
    const int row  = blockIdx.x * 4 + (threadIdx.x >> 6);
    const float2 x = *(const float2*)(z + (size_t)row * 128 + lane * 2);
    const float mu = wsum(x.x + x.y) * (1.f / 128.f);
    const float d0 = x.x - mu, d1 = x.y - mu;
    const float var = wsum(d0 * d0 + d1 * d1) * (1.f / 128.f);
    const float rs = rsqrtf(var + EPSV);
    const float2 gg = *(const float2*)(g + lane * 2);
    const float2 bb = *(const float2*)(b + lane * 2);
    const float z0 = d0 * rs * gg.x + bb.x;
    const float z1 = d1 * rs * gg.y + bb.y;
    // Wb rows c0=2*lane, c1=2*lane+1 (each 8 heads)
    const float4 wa0 = *(const float4*)(Wb + lane * 16 + 0);
    const float4 wa1 = *(const float4*)(Wb + lane * 16 + 4);
    const float4 wb0 = *(const float4*)(Wb + lane * 16 + 8);
    const float4 wb1 = *(const float4*)(Wb + lane * 16 + 12);
    float p[8];
    p[0] = z0 * wa0.x + z1 * wb0.x;
    p[1] = z0 * wa0.y + z1 * wb0.y;
    p[2] = z0 * wa0.z + z1 * wb0.z;
    p[3] = z0 * wa0.w + z1 * wb0.w;
    p[4] = z0 * wa1.x + z1 * wb1.x;
    p[5] = z0 * wa1.y + z1 * wb1.y;
    p[6] = z0 * wa1.z + z1 * wb1.z;
    p[7] = z0 * wa1.w + z1 * wb1.w;
#pragma unroll
    for (int h = 0; h < 8; ++h) p[h] = wsum(p[h]);
    float v = p[0];
#pragma unroll
    for (int h = 1; h < 8; ++h) v = (lane == h) ? p[h] : v;
    if (lane < 8) pb[(size_t)lane * 65536 + row] = v;
}

// -------- K3: fused QKVG projection + attention + gate, per (n,h) --------
__global__ __launch_bounds__(256) void k_attn(const ushort_t* __restrict__ mn,
                                              const float* __restrict__ pb,
                                              const int* __restrict__ msa_mask,
                                              const float* __restrict__ Wq,
                                              const float* __restrict__ Wk,
                                              const float* __restrict__ Wv,
                                              const float* __restrict__ Wg,
                                              const float* __restrict__ bg,
                                              ushort_t* __restrict__ ao) {
    __shared__ float As[256][20];       // 20480 B
    __shared__ float Ws[16][128];       // 8192 B
    __shared__ ushort_t q_s[256 * 32];  // 16384 B
    __shared__ ushort_t k_s[256 * 32];
    __shared__ ushort_t v_s[256 * 32];
    __shared__ ushort_t g_s[256 * 32];
    __shared__ float pb_s[256][33];     // 33792 B
    __shared__ float maskb[256];
    __shared__ float bg_s[32];

    const int t = threadIdx.x;
    const int n = blockIdx.x >> 3, h = blockIdx.x & 7;

    maskb[t] = msa_mask[n * 256 + t] ? 0.f : -1e9f;
    if (t < 32) bg_s[t] = bg[h * 32 + t];

    const int tx = t & 15, ty = t >> 4;
    const ushort_t* mrow = mn + (size_t)n * 65536;

    // ---- Phase A: q,k,v,g projections (fp32 compute, bf16 in/out) ----
    for (int half = 0; half < 2; ++half) {
        const int i0 = half * 128;
        float acc[8][8];
#pragma unroll
        for (int r = 0; r < 8; ++r)
#pragma unroll
            for (int c = 0; c < 8; ++c) acc[r][c] = 0.f;

        for (int chunk = 0; chunk < 16; ++chunk) {
            const int k0 = chunk * 16;
            __syncthreads();
            {   // stage A: row t, 16 k-elems
                const uint4 u0 = *(const uint4*)(mrow + t * 256 + k0);
                const uint4 u1 = *(const uint4*)(mrow + t * 256 + k0 + 8);
                float4 f0 = {bflo(u0.x), bfhi(u0.x), bflo(u0.y), bfhi(u0.y)};
                float4 f1 = {bflo(u0.z), bfhi(u0.z), bflo(u0.w), bfhi(u0.w)};
                float4 f2 = {bflo(u1.x), bfhi(u1.x), bflo(u1.y), bfhi(u1.y)};
                float4 f3 = {bflo(u1.z), bfhi(u1.z), bflo(u1.w), bfhi(u1.w)};
                *(float4*)&As[t][0]  = f0;
                *(float4*)&As[t][4]  = f1;
                *(float4*)&As[t][8]  = f2;
                *(float4*)&As[t][12] = f3;
            }
            {   // stage W slices (c: 0-31 q, 32-63 k, 64-95 v, 96-127 g)
                const int c = (t & 31) * 4;
                const int mat = c >> 5;
                const int ch = c & 31;
                const float* W = (mat == 0) ? Wq : (mat == 1) ? Wk : (mat == 2) ? Wv : Wg;
#pragma unroll
                for (int p = 0; p < 2; ++p) {
                    const int kk = p * 8 + (t >> 5);
                    *(float4*)&Ws[kk][c] = *(const float4*)(W + (size_t)(k0 + kk) * 256 + h * 32 + ch);
                }
            }
            __syncthreads();
#pragma unroll 4
            for (int kk = 0; kk < 16; ++kk) {
                float a[8];
#pragma unroll
                for (int r = 0; r < 8; ++r) a[r] = As[i0 + ty + 16 * r][kk];
                const float4 b0 = *(const float4*)&Ws[kk][tx * 8];
                const float4 b1 = *(const float4*)&Ws[kk][tx * 8 + 4];
                const float bb[8] = {b0.x, b0.y, b0.z, b0.w, b1.x, b1.y, b1.z, b1.w};
#pragma unroll
                for (int r = 0; r < 8; ++r)
#pragma unroll
                    for (int c = 0; c < 8; ++c) acc[r][c] += a[r] * bb[c];
            }
        }
        __syncthreads();
        {   // epilogue: write bf16 outputs to LDS
            const int mat = tx >> 2;
            const int ch0 = (tx & 3) * 8;
            ushort_t* outp = (mat == 0) ? q_s : (mat == 1) ? k_s : (mat == 2) ? v_s : g_s;
#pragma unroll
            for (int r = 0; r < 8; ++r) {
                const int i = i0 + ty + 16 * r;
#pragma unroll
                for (int c = 0; c < 8; ++c) outp[i * 32 + ch0 + c] = f2bf(acc[r][c]);
            }
        }
    }
    __syncthreads();

    // ---- Phase B: attention, thread t owns row i=t ----
    float qr[32];
    {
        const uint4* qp = (const uint4*)&q_s[t * 32];
#pragma unroll
        for (int w = 0; w < 4; ++w) {
            const uint4 u = qp[w];
            qr[w * 8 + 0] = bflo(u.x) * SCALE; qr[w * 8 + 1] = bfhi(u.x) * SCALE;
            qr[w * 8 + 2] = bflo(u.y) * SCALE; qr[w * 8 + 3] = bfhi(u.y) * SCALE;
            qr[w * 8 + 4] = bflo(u.z) * SCALE; qr[w * 8 + 5] = bfhi(u.z) * SCALE;
            qr[w * 8 + 6] = bflo(u.w) * SCALE; qr[w * 8 + 7] = bfhi(u.w) * SCALE;
        }
    }
    const float* pbh = pb + (size_t)h * 65536;

    float mrun = -1e30f;
    // pass 1: row max
    for (int chunk = 0; chunk < 8; ++chunk) {
        const int j0 = chunk * 32;
        __syncthreads();
#pragma unroll
        for (int e = 0; e < 32; ++e) {
            const int i = e * 8 + (t >> 5);
            pb_s[i][t & 31] = pbh[i * 256 + j0 + (t & 31)];
        }
        __syncthreads();
#pragma unroll 4
        for (int jj = 0; jj < 32; ++jj) {
            const int j = j0 + jj;
            const uint4* kp = (const uint4*)&k_s[j * 32];
            float s = 0.f;
#pragma unroll
            for (int w = 0; w < 4; ++w) {
                const uint4 u = kp[w];
                s += qr[w * 8 + 0] * bflo(u.x) + qr[w * 8 + 1] * bfhi(u.x);
                s += qr[w * 8 + 2] * bflo(u.y) + qr[w * 8 + 3] * bfhi(u.y);
                s += qr[w * 8 + 4] * bflo(u.z) + qr[w * 8 + 5] * bfhi(u.z);
                s += qr[w * 8 + 6] * bflo(u.w) + qr[w * 8 + 7] * bfhi(u.w);
            }
            s += pb_s[t][jj] + maskb[j];
            mrun = fmaxf(mrun, s);
        }
    }
    // pass 2: exp-sum and PV
    float lsum = 0.f;
    float O[32];
#pragma unroll
    for (int c = 0; c < 32; ++c) O[c] = 0.f;
    for (int chunk = 0; chunk < 8; ++chunk) {
        const int j0 = chunk * 32;
        __syncthreads();
#pragma unroll
        for (int e = 0; e < 32; ++e) {
            const int i = e * 8 + (t >> 5);
            pb_s[i][t & 31] = pbh[i * 256 + j0 + (t & 31)];
        }
        __syncthreads();
#pragma unroll 2
        for (int jj = 0; jj < 32; ++jj) {
            const int j = j0 + jj;
            const uint4* kp = (const uint4*)&k_s[j * 32];
            float s = 0.f;
#pragma unroll
            for (int w = 0; w < 4; ++w) {
                const uint4 u = kp[w];
                s += qr[w * 8 + 0] * bflo(u.x) + qr[w * 8 + 1] * bfhi(u.x);
                s += qr[w * 8 + 2] * bflo(u.y) + qr[w * 8 + 3] * bfhi(u.y);
                s += qr[w * 8 + 4] * bflo(u.z) + qr[w * 8 + 5] * bfhi(u.z);
                s += qr[w * 8 + 6] * bflo(u.w) + qr[w * 8 + 7] * bfhi(u.w);
            }
            s += pb_s[t][jj] + maskb[j];
            const float p = __expf(s - mrun);
            lsum += p;
            const uint4* vp = (const uint4*)&v_s[j * 32];
#pragma unroll
            for (int w = 0; w < 4; ++w) {
                const uint4 u = vp[w];
                O[w * 8 + 0] += p * bflo(u.x); O[w * 8 + 1] += p * bfhi(u.x);
                O[w * 8 + 2] += p * bflo(u.y); O[w * 8 + 3] += p * bfhi(u.y);
                O[w * 8 + 4] += p * bflo(u.z); O[w * 8 + 5] += p * bfhi(u.z);
                O[w * 8 + 6] += p * bflo(u.w); O[w * 8 + 7] += p * bfhi(u.w);
            }
        }
    }
    // epilogue: gate + write
    const float inv = 1.f / lsum;
    ushort_t* aop = ao + ((size_t)n * 256 + t) * 256 + h * 32;
#pragma unroll
    for (int ch = 0; ch < 32; ++ch) {
        const float gx = u2f(((uint_t)g_s[t * 32 + ch]) << 16);
        const float gate = 1.f / (1.f + __expf(-(gx + bg_s[ch])));
        aop[ch] = f2bf(O[ch] * inv * gate);
    }
}

// -------- K4: out = ao @ Wo + bo, row-masked --------
__global__ __launch_bounds__(256) void k_out(const ushort_t* __restrict__ ao,
                                             const float* __restrict__ Wo,
                                             const float* __restrict__ bo,
                                             const int* __restrict__ msa_mask,
                                             float* __restrict__ out) {
    __shared__ float As[64][36];
    __shared__ float Bs[32][260];
    const int t = threadIdx.x;
    const int rb = blockIdx.x * 64;
    const int tx = t & 31, ty = t >> 5;
    float acc[8][8];
#pragma unroll
    for (int r = 0; r < 8; ++r)
#pragma unroll
        for (int c = 0; c < 8; ++c) acc[r][c] = 0.f;

    for (int chunk = 0; chunk < 8; ++chunk) {
        const int k0 = chunk * 32;
        __syncthreads();
        {   // stage A chunk (bf16 -> f32)
            const int r = t >> 2, kk0 = (t & 3) * 8;
            const uint4 u = *(const uint4*)(ao + (size_t)(rb + r) * 256 + k0 + kk0);
            float4 f0 = {bflo(u.x), bfhi(u.x), bflo(u.y), bfhi(u.y)};
            float4 f1 = {bflo(u.z), bfhi(u.z), bflo(u.w), bfhi(u.w)};
            *(float4*)&As[r][kk0]     = f0;
            *(float4*)&As[r][kk0 + 4] = f1;
        }
        {   // stage B chunk
            const int c = (t & 63) * 4;
#pragma unroll
            for (int p = 0; p < 8; ++p) {
                const int kk = p * 4 + (t >> 6);
                *(float4*)&Bs[kk][c] = *(const float4*)(Wo + (size_t)(k0 + kk) * 256 + c);
            }
        }
        __syncthreads();
#pragma unroll 4
        for (int kk = 0; kk < 32; ++kk) {
            float a[8];
#pragma unroll
            for (int r = 0; r < 8; ++r) a[r] = As[ty * 8 + r][kk];
            const float4 b0 = *(const float4*)&Bs[kk][tx * 8];
            const float4 b1 = *(const float4*)&Bs[kk][tx * 8 + 4];
            const float bb[8] = {b0.x, b0.y, b0.z, b0.w, b1.x, b1.y, b1.z, b1.w};
#pragma unroll
            for (int r = 0; r < 8; ++r)
#pragma unroll
                for (int c = 0; c < 8; ++c) acc[r][c] += a[r] * bb[c];
        }
    }
    const float4 bo0 = *(const float4*)(bo + tx * 8);
    const float4 bo1 = *(const float4*)(bo + tx * 8 + 4);
#pragma unroll
    for (int r = 0; r < 8; ++r) {
        const int ri = rb + ty * 8 + r;
        const float mk = msa_mask[ri] ? 1.f : 0.f;
        float4 o0, o1;
        o0.x = (acc[r][0] + bo0.x) * mk; o0.y = (acc[r][1] + bo0.y) * mk;
        o0.z = (acc[r][2] + bo0.z) * mk; o0.w = (acc[r][3] + bo0.w) * mk;
        o1.x = (acc[r][4] + bo1.x) * mk; o1.y = (acc[r][5] + bo1.y) * mk;
        o1.z = (acc[r][6] + bo1.z) * mk; o1.w = (acc[r][7] + bo1.w) * mk;
        *(float4*)(out + (size_t)ri * 256 + tx * 8)     = o0;
        *(float4*)(out + (size_t)ri * 256 + tx * 8 + 4) = o1;
    }
}

extern "C" void kernel_launch(void* const* d_in, const int* in_sizes, int n_in,
                              void* d_out, int out_size, void* d_ws, size_t ws_size,
                              hipStream_t stream) {
    const float* m       = (const float*)d_in[0];
    const float* z       = (const float*)d_in[1];
    const int* msa_mask  = (const int*)d_in[2];
    const float* ln_m_g  = (const float*)d_in[3];
    const float* ln_m_b  = (const float*)d_in[4];
    const float* ln_z_g  = (const float*)d_in[5];
    const float* ln_z_b  = (const float*)d_in[6];
    const float* Wq      = (const float*)d_in[7];
    const float* Wk      = (const float*)d_in[8];
    const float* Wv      = (const float*)d_in[9];
    const float* Wb      = (const float*)d_in[10];
    const float* Wg      = (const float*)d_in[11];
    const float* bg      = (const float*)d_in[12];
    const float* Wo      = (const float*)d_in[13];
    const float* bo      = (const float*)d_in[14];
    float* out           = (float*)d_out;

    ushort_t* mn = (ushort_t*)d_ws;                                   // 33,554,432 B
    float* pb    = (float*)((char*)d_ws + 33554432);                  //  2,097,152 B
    ushort_t* ao = (ushort_t*)((char*)d_ws + 33554432 + 2097152);     // 33,554,432 B

    k_ln_m<<<16384, 256, 0, stream>>>(m, ln_m_g, ln_m_b, mn);
    k_pair_bias<<<16384, 256, 0, stream>>>(z, ln_z_g, ln_z_b, Wb, pb);
    k_attn<<<2048, 256, 0, stream>>>(mn, pb, msa_mask, Wq, Wk, Wv, Wg, bg, ao);
    k_out<<<1024, 256, 0, stream>>>(ao, Wo, bo, msa_mask, out);
}

// Round 2
// 314.113 us; speedup vs baseline: 6.1930x; 6.1930x over previous
//
#include <hip/hip_runtime.h>

typedef unsigned short ushort_t;
typedef unsigned int uint_t;
typedef __attribute__((ext_vector_type(8))) short bf16x8;
typedef __attribute__((ext_vector_type(4))) float f32x4;

#define EPSV 1e-5f
#define SCALE 0.17677669529663687f  // 1/sqrt(32)

__device__ __forceinline__ float u2f(uint_t x) { return __builtin_bit_cast(float, x); }
__device__ __forceinline__ uint_t f2u(float x) { return __builtin_bit_cast(uint_t, x); }
__device__ __forceinline__ float bflo(uint_t u) { return u2f(u << 16); }
__device__ __forceinline__ float bfhi(uint_t u) { return u2f(u & 0xFFFF0000u); }
__device__ __forceinline__ ushort_t f2bf(float f) {
    uint_t x = f2u(f);
    x += 0x7FFFu + ((x >> 16) & 1u);   // RNE
    return (ushort_t)(x >> 16);
}
__device__ __forceinline__ f32x4 mfma16(bf16x8 a, bf16x8 b, f32x4 c) {
    return __builtin_amdgcn_mfma_f32_16x16x32_bf16(a, b, c, 0, 0, 0);
}
__device__ __forceinline__ float wsum(float v) {
#pragma unroll
    for (int m = 32; m >= 1; m >>= 1) v += __shfl_xor(v, m, 64);
    return v;
}

// -------- K0: pack transposed bf16 weights: wtT[h][c(128)][k(256)], woT[c][k] --------
__global__ __launch_bounds__(256) void k_prep(const float* __restrict__ Wq, const float* __restrict__ Wk,
                                              const float* __restrict__ Wv, const float* __restrict__ Wg,
                                              const float* __restrict__ Wo,
                                              ushort_t* __restrict__ wtT, ushort_t* __restrict__ woT) {
    const int k = blockIdx.x, t = threadIdx.x;
    const int h = t >> 5, c = t & 31;
    wtT[(size_t)(h * 128 +   0 + c) * 256 + k] = f2bf(Wq[k * 256 + t]);
    wtT[(size_t)(h * 128 +  32 + c) * 256 + k] = f2bf(Wk[k * 256 + t]);
    wtT[(size_t)(h * 128 +  64 + c) * 256 + k] = f2bf(Wv[k * 256 + t]);
    wtT[(size_t)(h * 128 +  96 + c) * 256 + k] = f2bf(Wg[k * 256 + t]);
    woT[(size_t)t * 256 + k] = f2bf(Wo[k * 256 + t]);
}

// -------- K1: LayerNorm(m) -> mn (bf16) --------
__global__ __launch_bounds__(256) void k_ln_m(const float* __restrict__ m,
                                              const float* __restrict__ g,
                                              const float* __restrict__ b,
                                              ushort_t* __restrict__ mn) {
    const int lane = threadIdx.x & 63;
    const int row  = blockIdx.x * 4 + (threadIdx.x >> 6);
    const float4 x = *(const float4*)(m + (size_t)row * 256 + lane * 4);
    const float mu = wsum(x.x + x.y + x.z + x.w) * (1.f / 256.f);
    const float dx = x.x - mu, dy = x.y - mu, dz = x.z - mu, dw = x.w - mu;
    const float var = wsum(dx * dx + dy * dy + dz * dz + dw * dw) * (1.f / 256.f);
    const float rs = rsqrtf(var + EPSV);
    const float4 gg = *(const float4*)(g + lane * 4);
    const float4 bb = *(const float4*)(b + lane * 4);
    ushort4 o;
    o.x = f2bf(dx * rs * gg.x + bb.x);
    o.y = f2bf(dy * rs * gg.y + bb.y);
    o.z = f2bf(dz * rs * gg.z + bb.z);
    o.w = f2bf(dw * rs * gg.w + bb.w);
    *(ushort4*)(mn + (size_t)row * 256 + lane * 4) = o;
}

// -------- K2: LayerNorm(z) @ Wb -> pb[h][i][j] (f32) --------
__global__ __launch_bounds__(256) void k_pair_bias(const float* __restrict__ z,
                                                   const float* __restrict__ g,
                                                   const float* __restrict__ b,
                                                   const float* __restrict__ Wb,
                                                   float* __restrict__ pb) {
    const int lane = threadIdx.x & 63;
    const int row  = blockIdx.x * 4 + (threadIdx.x >> 6);
    const float2 x = *(const float2*)(z + (size_t)row * 128 + lane * 2);
    const float mu = wsum(x.x + x.y) * (1.f / 128.f);
    const float d0 = x.x - mu, d1 = x.y - mu;
    const float var = wsum(d0 * d0 + d1 * d1) * (1.f / 128.f);
    const float rs = rsqrtf(var + EPSV);
    const float2 gg = *(const float2*)(g + lane * 2);
    const float2 bb = *(const float2*)(b + lane * 2);
    const float z0 = d0 * rs * gg.x + bb.x;
    const float z1 = d1 * rs * gg.y + bb.y;
    const float4 wa0 = *(const float4*)(Wb + lane * 16 + 0);
    const float4 wa1 = *(const float4*)(Wb + lane * 16 + 4);
    const float4 wb0 = *(const float4*)(Wb + lane * 16 + 8);
    const float4 wb1 = *(const float4*)(Wb + lane * 16 + 12);
    float p[8];
    p[0] = z0 * wa0.x + z1 * wb0.x;
    p[1] = z0 * wa0.y + z1 * wb0.y;
    p[2] = z0 * wa0.z + z1 * wb0.z;
    p[3] = z0 * wa0.w + z1 * wb0.w;
    p[4] = z0 * wa1.x + z1 * wb1.x;
    p[5] = z0 * wa1.y + z1 * wb1.y;
    p[6] = z0 * wa1.z + z1 * wb1.z;
    p[7] = z0 * wa1.w + z1 * wb1.w;
#pragma unroll
    for (int h = 0; h < 8; ++h) p[h] = wsum(p[h]);
    float v = p[0];
#pragma unroll
    for (int h = 1; h < 8; ++h) v = (lane == h) ? p[h] : v;
    if (lane < 8) pb[(size_t)lane * 65536 + row] = v;
}

// -------- K3: MFMA fused QKVG projection + flash attention + gate, per (n,h) --------
__global__ __launch_bounds__(256, 1) void k_attn(const ushort_t* __restrict__ mn,
                                                 const ushort_t* __restrict__ wtT,
                                                 const float* __restrict__ pb,
                                                 const int* __restrict__ msa_mask,
                                                 const float* __restrict__ bg,
                                                 ushort_t* __restrict__ ao) {
    __shared__ ushort_t q_s[256 * 40];   // [i][c], 80B rows (stride 20 words -> 2-way max)
    __shared__ ushort_t k_s[256 * 40];   // [j][c]
    __shared__ ushort_t vT[32 * 264];    // [c][j], +8 pad
    __shared__ ushort_t gT[32 * 264];    // [c][i]
    __shared__ ushort_t p_s[4 * 16 * 40];// per-wave [i16][j32], 80B rows
    __shared__ float maskb[256];
    __shared__ float bg_s[32];

    const int t = threadIdx.x;
    const int n = blockIdx.x >> 3, h = blockIdx.x & 7;
    const int w = t >> 6, l = t & 63;
    const int l16 = l & 15, g = l >> 4;

    maskb[t] = msa_mask[n * 256 + t] ? 0.f : -1e9f;
    if (t < 32) bg_s[t] = bg[h * 32 + t];

    const ushort_t* mb = mn + (size_t)n * 65536;
    const ushort_t* wb = wtT + (size_t)h * 128 * 256;

    // ---- Phase A: qkvg[i][c] = mn[i][:] @ W[:,c] via MFMA ----
#pragma unroll
    for (int chalf = 0; chalf < 2; ++chalf) {
        f32x4 acc[4][4];
#pragma unroll
        for (int rt = 0; rt < 4; ++rt)
#pragma unroll
            for (int ct = 0; ct < 4; ++ct) acc[rt][ct] = (f32x4){0.f, 0.f, 0.f, 0.f};

#pragma unroll
        for (int ks = 0; ks < 8; ++ks) {
            bf16x8 a[4], b[4];
#pragma unroll
            for (int rt = 0; rt < 4; ++rt)
                a[rt] = *(const bf16x8*)(mb + (size_t)(w * 64 + rt * 16 + l16) * 256 + ks * 32 + g * 8);
#pragma unroll
            for (int ct = 0; ct < 4; ++ct)
                b[ct] = *(const bf16x8*)(wb + (size_t)(chalf * 64 + ct * 16 + l16) * 256 + ks * 32 + g * 8);
#pragma unroll
            for (int rt = 0; rt < 4; ++rt)
#pragma unroll
                for (int ct = 0; ct < 4; ++ct)
                    acc[rt][ct] = mfma16(a[rt], b[ct], acc[rt][ct]);
        }
        // epilogue: C-frag lane holds [row = g*4+r][col = l16]
#pragma unroll
        for (int ct = 0; ct < 4; ++ct) {
            const int mat = chalf * 2 + (ct >> 1);       // 0 q, 1 k, 2 v, 3 g (uniform)
            const int cc = (ct & 1) * 16 + l16;          // 0..31 within matrix
#pragma unroll
            for (int rt = 0; rt < 4; ++rt) {
                const int i0 = w * 64 + rt * 16 + g * 4;
                const f32x4 v = acc[rt][ct];
                if (mat == 0) {
#pragma unroll
                    for (int r = 0; r < 4; ++r) q_s[(i0 + r) * 40 + cc] = f2bf(v[r]);
                } else if (mat == 1) {
#pragma unroll
                    for (int r = 0; r < 4; ++r) k_s[(i0 + r) * 40 + cc] = f2bf(v[r]);
                } else {
                    const uint_t lo = (uint_t)f2bf(v[0]) | ((uint_t)f2bf(v[1]) << 16);
                    const uint_t hi = (uint_t)f2bf(v[2]) | ((uint_t)f2bf(v[3]) << 16);
                    ushort_t* dst = (mat == 2 ? vT : gT) + cc * 264 + i0;
                    *(uint2*)dst = make_uint2(lo, hi);
                }
            }
        }
    }
    __syncthreads();

    // ---- Phase B: flash attention over j, wave w owns i in [w*64, w*64+64) ----
    const float* pbh = pb + (size_t)h * 65536;
    f32x4 oT[2][4];
#pragma unroll
    for (int ct = 0; ct < 2; ++ct)
#pragma unroll
        for (int it = 0; it < 4; ++it) oT[ct][it] = (f32x4){0.f, 0.f, 0.f, 0.f};
    float mrun[4] = {-1e30f, -1e30f, -1e30f, -1e30f};
    float lrun[4] = {0.f, 0.f, 0.f, 0.f};

    for (int jc = 0; jc < 8; ++jc) {
        // S^T = mfma(K, Q): D[j][i]
        bf16x8 ak[2], bq[4];
#pragma unroll
        for (int jt = 0; jt < 2; ++jt)
            ak[jt] = *(const bf16x8*)&k_s[(jc * 32 + jt * 16 + l16) * 40 + g * 8];
#pragma unroll
        for (int it = 0; it < 4; ++it)
            bq[it] = *(const bf16x8*)&q_s[(w * 64 + it * 16 + l16) * 40 + g * 8];
        f32x4 st[2][4];
#pragma unroll
        for (int jt = 0; jt < 2; ++jt)
#pragma unroll
            for (int it = 0; it < 4; ++it)
                st[jt][it] = mfma16(ak[jt], bq[it], (f32x4){0.f, 0.f, 0.f, 0.f});

        const f32x4 mk0 = *(const f32x4*)&maskb[jc * 32 + g * 4];
        const f32x4 mk1 = *(const f32x4*)&maskb[jc * 32 + 16 + g * 4];
        bf16x8 av[2];
#pragma unroll
        for (int ct = 0; ct < 2; ++ct)
            av[ct] = *(const bf16x8*)&vT[(ct * 16 + l16) * 264 + jc * 32 + g * 8];

#pragma unroll
        for (int it = 0; it < 4; ++it) {
            const int i = w * 64 + it * 16 + l16;
            const f32x4 pb0 = *(const f32x4*)(pbh + (size_t)i * 256 + jc * 32 + g * 4);
            const f32x4 pb1 = *(const f32x4*)(pbh + (size_t)i * 256 + jc * 32 + 16 + g * 4);
            float s0[4], s1[4];
#pragma unroll
            for (int r = 0; r < 4; ++r) {
                s0[r] = st[0][it][r] * SCALE + pb0[r] + mk0[r];
                s1[r] = st[1][it][r] * SCALE + pb1[r] + mk1[r];
            }
            float tmax = fmaxf(fmaxf(fmaxf(s0[0], s0[1]), fmaxf(s0[2], s0[3])),
                               fmaxf(fmaxf(s1[0], s1[1]), fmaxf(s1[2], s1[3])));
            tmax = fmaxf(tmax, __shfl_xor(tmax, 16, 64));
            tmax = fmaxf(tmax, __shfl_xor(tmax, 32, 64));
            const float mnew = fmaxf(mrun[it], tmax);
            const float fsc = __expf(mrun[it] - mnew);
            mrun[it] = mnew;
            float p0[4], p1[4], ps = 0.f;
#pragma unroll
            for (int r = 0; r < 4; ++r) { p0[r] = __expf(s0[r] - mnew); ps += p0[r]; }
#pragma unroll
            for (int r = 0; r < 4; ++r) { p1[r] = __expf(s1[r] - mnew); ps += p1[r]; }
            ps += __shfl_xor(ps, 16, 64);
            ps += __shfl_xor(ps, 32, 64);
            lrun[it] = lrun[it] * fsc + ps;
#pragma unroll
            for (int r = 0; r < 4; ++r) { oT[0][it][r] *= fsc; oT[1][it][r] *= fsc; }
            // write P (bf16) to per-wave p_s[i16][j32]: lane holds i=l16, j=jt*16+g*4+r
            {
                const uint_t a0 = (uint_t)f2bf(p0[0]) | ((uint_t)f2bf(p0[1]) << 16);
                const uint_t a1 = (uint_t)f2bf(p0[2]) | ((uint_t)f2bf(p0[3]) << 16);
                const uint_t b0 = (uint_t)f2bf(p1[0]) | ((uint_t)f2bf(p1[1]) << 16);
                const uint_t b1 = (uint_t)f2bf(p1[2]) | ((uint_t)f2bf(p1[3]) << 16);
                ushort_t* base = &p_s[(w * 16 + l16) * 40];
                *(uint2*)(base + g * 4)      = make_uint2(a0, a1);
                *(uint2*)(base + 16 + g * 4) = make_uint2(b0, b1);
            }
            const bf16x8 bp = *(const bf16x8*)&p_s[(w * 16 + l16) * 40 + g * 8];
            oT[0][it] = mfma16(av[0], bp, oT[0][it]);
            oT[1][it] = mfma16(av[1], bp, oT[1][it]);
        }
    }

    float inv[4];
#pragma unroll
    for (int it = 0; it < 4; ++it) inv[it] = 1.f / lrun[it];

    __syncthreads();                      // all waves done with vT reads
    ushort_t* oT_s = vT;                  // reuse as gated-output transpose buffer
#pragma unroll
    for (int ct = 0; ct < 2; ++ct)
#pragma unroll
        for (int it = 0; it < 4; ++it) {
            const int i = w * 64 + it * 16 + l16;
#pragma unroll
            for (int r = 0; r < 4; ++r) {
                const int c = ct * 16 + g * 4 + r;
                const float gx = bflo((uint_t)gT[c * 264 + i]);
                const float gate = 1.f / (1.f + __expf(-(gx + bg_s[c])));
                oT_s[c * 264 + i] = f2bf(oT[ct][it][r] * inv[it] * gate);
            }
        }
    __syncthreads();
    // coalesced bf16x2 store to ao[n*256+i][h*32+c]
    ushort_t* aob = ao + (size_t)n * 256 * 256 + h * 32;
#pragma unroll
    for (int iter = 0; iter < 16; ++iter) {
        const int flat = iter * 256 + t;
        const int i = flat >> 4, cp = flat & 15;
        const uint_t lo = oT_s[(2 * cp) * 264 + i];
        const uint_t hi = oT_s[(2 * cp + 1) * 264 + i];
        *(uint_t*)(aob + (size_t)i * 256 + 2 * cp) = lo | (hi << 16);
    }
}

// -------- K4: out = ao @ Wo + bo (MFMA), row-masked --------
__global__ __launch_bounds__(256, 2) void k_out(const ushort_t* __restrict__ ao,
                                                const ushort_t* __restrict__ woT,
                                                const float* __restrict__ bo,
                                                const int* __restrict__ msa_mask,
                                                float* __restrict__ out) {
    const int t = threadIdx.x;
    const int rb = blockIdx.x * 128;
    const int w = t >> 6, l = t & 63;
    const int l16 = l & 15, g = l >> 4;

#pragma unroll
    for (int ch = 0; ch < 2; ++ch) {
        f32x4 acc[2][8];
#pragma unroll
        for (int rt = 0; rt < 2; ++rt)
#pragma unroll
            for (int ct = 0; ct < 8; ++ct) acc[rt][ct] = (f32x4){0.f, 0.f, 0.f, 0.f};
#pragma unroll
        for (int ks = 0; ks < 8; ++ks) {
            bf16x8 a[2], b[8];
#pragma unroll
            for (int rt = 0; rt < 2; ++rt)
                a[rt] = *(const bf16x8*)(ao + (size_t)(rb + w * 32 + rt * 16 + l16) * 256 + ks * 32 + g * 8);
#pragma unroll
            for (int ct = 0; ct < 8; ++ct)
                b[ct] = *(const bf16x8*)(woT + (size_t)(ch * 128 + ct * 16 + l16) * 256 + ks * 32 + g * 8);
#pragma unroll
            for (int rt = 0; rt < 2; ++rt)
#pragma unroll
                for (int ct = 0; ct < 8; ++ct)
                    acc[rt][ct] = mfma16(a[rt], b[ct], acc[rt][ct]);
        }
#pragma unroll
        for (int rt = 0; rt < 2; ++rt)
#pragma unroll
            for (int ct = 0; ct < 8; ++ct) {
                const int c = ch * 128 + ct * 16 + l16;
                const float boc = bo[c];
#pragma unroll
                for (int r = 0; r < 4; ++r) {
                    const int row = rb + w * 32 + rt * 16 + g * 4 + r;
                    const float mk = msa_mask[row] ? 1.f : 0.f;
                    out[(size_t)row * 256 + c] = (acc[rt][ct][r] + boc) * mk;
                }
            }
    }
}

extern "C" void kernel_launch(void* const* d_in, const int* in_sizes, int n_in,
                              void* d_out, int out_size, void* d_ws, size_t ws_size,
                              hipStream_t stream) {
    const float* m       = (const float*)d_in[0];
    const float* z       = (const float*)d_in[1];
    const int* msa_mask  = (const int*)d_in[2];
    const float* ln_m_g  = (const float*)d_in[3];
    const float* ln_m_b  = (const float*)d_in[4];
    const float* ln_z_g  = (const float*)d_in[5];
    const float* ln_z_b  = (const float*)d_in[6];
    const float* Wq      = (const float*)d_in[7];
    const float* Wk      = (const float*)d_in[8];
    const float* Wv      = (const float*)d_in[9];
    const float* Wb      = (const float*)d_in[10];
    const float* Wg      = (const float*)d_in[11];
    const float* bg      = (const float*)d_in[12];
    const float* Wo      = (const float*)d_in[13];
    const float* bo      = (const float*)d_in[14];
    float* out           = (float*)d_out;

    char* ws = (char*)d_ws;
    ushort_t* mn  = (ushort_t*)(ws);                    // 33,554,432 B
    float*    pb  = (float*)(ws + 33554432);            //  2,097,152 B
    ushort_t* ao  = (ushort_t*)(ws + 35651584);         // 33,554,432 B
    ushort_t* wtT = (ushort_t*)(ws + 69206016);         //    524,288 B
    ushort_t* woT = (ushort_t*)(ws + 69730304);         //    131,072 B

    k_prep<<<256, 256, 0, stream>>>(Wq, Wk, Wv, Wg, Wo, wtT, woT);
    k_ln_m<<<16384, 256, 0, stream>>>(m, ln_m_g, ln_m_b, mn);
    k_pair_bias<<<16384, 256, 0, stream>>>(z, ln_z_g, ln_z_b, Wb, pb);
    k_attn<<<2048, 256, 0, stream>>>(mn, wtT, pb, msa_mask, bg, ao);
    k_out<<<512, 256, 0, stream>>>(ao, woT, bo, msa_mask, out);
}

// Round 3
// 299.310 us; speedup vs baseline: 6.4993x; 1.0495x over previous
//
#include <hip/hip_runtime.h>

typedef unsigned short ushort_t;
typedef unsigned int uint_t;
typedef __attribute__((ext_vector_type(8))) short bf16x8;
typedef __attribute__((ext_vector_type(4))) float f32x4;

#define EPSV 1e-5f
#define LOG2E 1.4426950408889634f
#define QSC (0.17677669529663687f * LOG2E)   // (1/sqrt(32)) * log2(e)

__device__ __forceinline__ float u2f(uint_t x) { return __builtin_bit_cast(float, x); }
__device__ __forceinline__ uint_t f2u(float x) { return __builtin_bit_cast(uint_t, x); }
__device__ __forceinline__ float bflo(uint_t u) { return u2f(u << 16); }
__device__ __forceinline__ float bfhi(uint_t u) { return u2f(u & 0xFFFF0000u); }
__device__ __forceinline__ ushort_t f2bf(float f) {
    uint_t x = f2u(f);
    x += 0x7FFFu + ((x >> 16) & 1u);   // RNE
    return (ushort_t)(x >> 16);
}
__device__ __forceinline__ uint_t cvtpk(float lo, float hi) {
    uint_t r;
    asm("v_cvt_pk_bf16_f32 %0, %1, %2" : "=v"(r) : "v"(lo), "v"(hi));
    return r;
}
__device__ __forceinline__ float exp2v(float x) {
    float r;
    asm("v_exp_f32 %0, %1" : "=v"(r) : "v"(x));
    return r;
}
__device__ __forceinline__ float rcpv(float x) {
    float r;
    asm("v_rcp_f32 %0, %1" : "=v"(r) : "v"(x));
    return r;
}
__device__ __forceinline__ f32x4 mfma16(bf16x8 a, bf16x8 b, f32x4 c) {
    return __builtin_amdgcn_mfma_f32_16x16x32_bf16(a, b, c, 0, 0, 0);
}
__device__ __forceinline__ float wsum(float v) {
#pragma unroll
    for (int m = 32; m >= 1; m >>= 1) v += __shfl_xor(v, m, 64);
    return v;
}

// -------- K0: pack transposed bf16 weights: wtT[h][c(128)][k(256)], woT[c][k] --------
__global__ __launch_bounds__(256) void k_prep(const float* __restrict__ Wq, const float* __restrict__ Wk,
                                              const float* __restrict__ Wv, const float* __restrict__ Wg,
                                              const float* __restrict__ Wo,
                                              ushort_t* __restrict__ wtT, ushort_t* __restrict__ woT) {
    const int k = blockIdx.x, t = threadIdx.x;
    const int h = t >> 5, c = t & 31;
    wtT[(size_t)(h * 128 +   0 + c) * 256 + k] = f2bf(Wq[k * 256 + t]);
    wtT[(size_t)(h * 128 +  32 + c) * 256 + k] = f2bf(Wk[k * 256 + t]);
    wtT[(size_t)(h * 128 +  64 + c) * 256 + k] = f2bf(Wv[k * 256 + t]);
    wtT[(size_t)(h * 128 +  96 + c) * 256 + k] = f2bf(Wg[k * 256 + t]);
    woT[(size_t)t * 256 + k] = f2bf(Wo[k * 256 + t]);
}

// -------- K1: LayerNorm(m) -> mn (bf16) --------
__global__ __launch_bounds__(256) void k_ln_m(const float* __restrict__ m,
                                              const float* __restrict__ g,
                                              const float* __restrict__ b,
                                              ushort_t* __restrict__ mn) {
    const int lane = threadIdx.x & 63;
    const int row  = blockIdx.x * 4 + (threadIdx.x >> 6);
    const float4 x = *(const float4*)(m + (size_t)row * 256 + lane * 4);
    const float mu = wsum(x.x + x.y + x.z + x.w) * (1.f / 256.f);
    const float dx = x.x - mu, dy = x.y - mu, dz = x.z - mu, dw = x.w - mu;
    const float var = wsum(dx * dx + dy * dy + dz * dz + dw * dw) * (1.f / 256.f);
    const float rs = rsqrtf(var + EPSV);
    const float4 gg = *(const float4*)(g + lane * 4);
    const float4 bb = *(const float4*)(b + lane * 4);
    ushort4 o;
    o.x = f2bf(dx * rs * gg.x + bb.x);
    o.y = f2bf(dy * rs * gg.y + bb.y);
    o.z = f2bf(dz * rs * gg.z + bb.z);
    o.w = f2bf(dw * rs * gg.w + bb.w);
    *(ushort4*)(mn + (size_t)row * 256 + lane * 4) = o;
}

// -------- K2: LayerNorm(z) @ Wb -> pb[h][i][j] (f32, pre-scaled by log2e) --------
__global__ __launch_bounds__(256) void k_pair_bias(const float* __restrict__ z,
                                                   const float* __restrict__ g,
                                                   const float* __restrict__ b,
                                                   const float* __restrict__ Wb,
                                                   float* __restrict__ pb) {
    const int lane = threadIdx.x & 63;
    const int row  = blockIdx.x * 4 + (threadIdx.x >> 6);
    const float2 x = *(const float2*)(z + (size_t)row * 128 + lane * 2);
    const float mu = wsum(x.x + x.y) * (1.f / 128.f);
    const float d0 = x.x - mu, d1 = x.y - mu;
    const float var = wsum(d0 * d0 + d1 * d1) * (1.f / 128.f);
    const float rs = rsqrtf(var + EPSV);
    const float2 gg = *(const float2*)(g + lane * 2);
    const float2 bb = *(const float2*)(b + lane * 2);
    const float z0 = d0 * rs * gg.x + bb.x;
    const float z1 = d1 * rs * gg.y + bb.y;
    const float4 wa0 = *(const float4*)(Wb + lane * 16 + 0);
    const float4 wa1 = *(const float4*)(Wb + lane * 16 + 4);
    const float4 wb0 = *(const float4*)(Wb + lane * 16 + 8);
    const float4 wb1 = *(const float4*)(Wb + lane * 16 + 12);
    float p[8];
    p[0] = z0 * wa0.x + z1 * wb0.x;
    p[1] = z0 * wa0.y + z1 * wb0.y;
    p[2] = z0 * wa0.z + z1 * wb0.z;
    p[3] = z0 * wa0.w + z1 * wb0.w;
    p[4] = z0 * wa1.x + z1 * wb1.x;
    p[5] = z0 * wa1.y + z1 * wb1.y;
    p[6] = z0 * wa1.z + z1 * wb1.z;
    p[7] = z0 * wa1.w + z1 * wb1.w;
#pragma unroll
    for (int h = 0; h < 8; ++h) p[h] = wsum(p[h]);
    float v = p[0];
#pragma unroll
    for (int h = 1; h < 8; ++h) v = (lane == h) ? p[h] : v;
    if (lane < 8) pb[(size_t)lane * 65536 + row] = v * LOG2E;
}

// -------- K3: MFMA fused QKVG projection + attention (no-max softmax) + gate --------
__global__ __launch_bounds__(256, 1) void k_attn(const ushort_t* __restrict__ mn,
                                                 const ushort_t* __restrict__ wtT,
                                                 const float* __restrict__ pb,
                                                 const int* __restrict__ msa_mask,
                                                 const float* __restrict__ bg,
                                                 ushort_t* __restrict__ ao) {
    __shared__ ushort_t k_s[256 * 40];   // [j][c], 80B rows
    __shared__ ushort_t qp_s[256 * 40];  // Phase A: q[i][c]; Phase B (after q->regs): P[w][i64][j32] per wave
    __shared__ ushort_t vT[32 * 264];    // [c][j], later reused as gated-output transpose
    __shared__ ushort_t gT[32 * 264];    // [c][i], holds sigmoid gate (bf16)
    __shared__ float maskb[256];

    const int t = threadIdx.x;
    const int n = blockIdx.x >> 3, h = blockIdx.x & 7;
    const int w = t >> 6, l = t & 63;
    const int l16 = l & 15, g = l >> 4;

    maskb[t] = msa_mask[n * 256 + t] ? 0.f : -1.5e9f;
    const float bg0 = bg[h * 32 + l16];
    const float bg1 = bg[h * 32 + 16 + l16];

    const ushort_t* mb = mn + (size_t)n * 65536;
    const ushort_t* wb = wtT + (size_t)h * 128 * 256;

    // ---- Phase A: qkvg[i][c] = mn[i][:] @ W[:,c] via MFMA ----
#pragma unroll
    for (int chalf = 0; chalf < 2; ++chalf) {
        f32x4 acc[4][4];
#pragma unroll
        for (int rt = 0; rt < 4; ++rt)
#pragma unroll
            for (int ct = 0; ct < 4; ++ct) acc[rt][ct] = (f32x4){0.f, 0.f, 0.f, 0.f};

#pragma unroll
        for (int ks = 0; ks < 8; ++ks) {
            bf16x8 a[4], b[4];
#pragma unroll
            for (int rt = 0; rt < 4; ++rt)
                a[rt] = *(const bf16x8*)(mb + (size_t)(w * 64 + rt * 16 + l16) * 256 + ks * 32 + g * 8);
#pragma unroll
            for (int ct = 0; ct < 4; ++ct)
                b[ct] = *(const bf16x8*)(wb + (size_t)(chalf * 64 + ct * 16 + l16) * 256 + ks * 32 + g * 8);
#pragma unroll
            for (int rt = 0; rt < 4; ++rt)
#pragma unroll
                for (int ct = 0; ct < 4; ++ct)
                    acc[rt][ct] = mfma16(a[rt], b[ct], acc[rt][ct]);
        }
        // epilogue: C-frag lane holds [row = g*4+r][col = l16]
#pragma unroll
        for (int ct = 0; ct < 4; ++ct) {
            const int mat = chalf * 2 + (ct >> 1);       // 0 q, 1 k, 2 v, 3 g
            const int cc = (ct & 1) * 16 + l16;
#pragma unroll
            for (int rt = 0; rt < 4; ++rt) {
                const int i0 = w * 64 + rt * 16 + g * 4;
                const f32x4 v = acc[rt][ct];
                if (mat == 0) {          // q: fold SCALE*log2e
#pragma unroll
                    for (int r = 0; r < 4; ++r) qp_s[(i0 + r) * 40 + cc] = f2bf(v[r] * QSC);
                } else if (mat == 1) {   // k
#pragma unroll
                    for (int r = 0; r < 4; ++r) k_s[(i0 + r) * 40 + cc] = f2bf(v[r]);
                } else if (mat == 2) {   // v -> transposed
                    const uint_t lo = cvtpk(v[0], v[1]);
                    const uint_t hi = cvtpk(v[2], v[3]);
                    *(uint2*)(vT + cc * 264 + i0) = make_uint2(lo, hi);
                } else {                 // g -> sigmoid gate, transposed
                    const float bgc = (ct & 1) ? bg1 : bg0;
                    float gt[4];
#pragma unroll
                    for (int r = 0; r < 4; ++r)
                        gt[r] = rcpv(1.f + exp2v(-(v[r] + bgc) * LOG2E));
                    const uint_t lo = cvtpk(gt[0], gt[1]);
                    const uint_t hi = cvtpk(gt[2], gt[3]);
                    *(uint2*)(gT + cc * 264 + i0) = make_uint2(lo, hi);
                }
            }
        }
    }
    __syncthreads();

    // ---- Phase B: attention. Wave w owns rows i in [w*64, w*64+64). ----
    // Hoist q fragments to registers, then reuse qp_s rows [w*64, w*64+64) as the
    // wave-private P buffer (no barrier needed: same-wave producer/consumer).
    bf16x8 bq[4];
#pragma unroll
    for (int it = 0; it < 4; ++it)
        bq[it] = *(const bf16x8*)&qp_s[(w * 64 + it * 16 + l16) * 40 + g * 8];
    ushort_t* p_w = qp_s + w * 64 * 40;

    const float* pbh = pb + (size_t)h * 65536;
    f32x4 oT[2][4];
#pragma unroll
    for (int ct = 0; ct < 2; ++ct)
#pragma unroll
        for (int it = 0; it < 4; ++it) oT[ct][it] = (f32x4){0.f, 0.f, 0.f, 0.f};
    float lsum[4] = {0.f, 0.f, 0.f, 0.f};

    for (int jc = 0; jc < 8; ++jc) {
        // issue pair-bias loads early (L2 latency hides under S-MFMAs)
        f32x4 pb0[4], pb1[4];
#pragma unroll
        for (int it = 0; it < 4; ++it) {
            const int i = w * 64 + it * 16 + l16;
            pb0[it] = *(const f32x4*)(pbh + (size_t)i * 256 + jc * 32 + g * 4);
            pb1[it] = *(const f32x4*)(pbh + (size_t)i * 256 + jc * 32 + 16 + g * 4);
        }
        bf16x8 ak[2], av[2];
#pragma unroll
        for (int jt = 0; jt < 2; ++jt)
            ak[jt] = *(const bf16x8*)&k_s[(jc * 32 + jt * 16 + l16) * 40 + g * 8];
#pragma unroll
        for (int ct = 0; ct < 2; ++ct)
            av[ct] = *(const bf16x8*)&vT[(ct * 16 + l16) * 264 + jc * 32 + g * 8];

        // S^T = mfma(K, Q): lane holds S[j = jc*32 + jt*16 + g*4 + r][i = it*16 + l16]
        f32x4 st[2][4];
#pragma unroll
        for (int jt = 0; jt < 2; ++jt)
#pragma unroll
            for (int it = 0; it < 4; ++it)
                st[jt][it] = mfma16(ak[jt], bq[it], (f32x4){0.f, 0.f, 0.f, 0.f});

        const f32x4 mk0 = *(const f32x4*)&maskb[jc * 32 + g * 4];
        const f32x4 mk1 = *(const f32x4*)&maskb[jc * 32 + 16 + g * 4];

        // softmax numerator (no max subtraction; logits are O(1), masked -> exp2(-1.5e9)=0)
#pragma unroll
        for (int it = 0; it < 4; ++it) {
            float p0[4], p1[4];
#pragma unroll
            for (int r = 0; r < 4; ++r) {
                p0[r] = exp2v(st[0][it][r] + pb0[it][r] + mk0[r]);
                p1[r] = exp2v(st[1][it][r] + pb1[it][r] + mk1[r]);
            }
#pragma unroll
            for (int r = 0; r < 4; ++r) lsum[it] += p0[r] + p1[r];
            ushort_t* base = p_w + (it * 16 + l16) * 40;
            *(uint2*)(base + g * 4)      = make_uint2(cvtpk(p0[0], p0[1]), cvtpk(p0[2], p0[3]));
            *(uint2*)(base + 16 + g * 4) = make_uint2(cvtpk(p1[0], p1[1]), cvtpk(p1[2], p1[3]));
        }
        // PV: O^T += mfma(V^T, P)
#pragma unroll
        for (int it = 0; it < 4; ++it) {
            const bf16x8 bp = *(const bf16x8*)&p_w[(it * 16 + l16) * 40 + g * 8];
            oT[0][it] = mfma16(av[0], bp, oT[0][it]);
            oT[1][it] = mfma16(av[1], bp, oT[1][it]);
        }
    }

    float inv[4];
#pragma unroll
    for (int it = 0; it < 4; ++it) {
        float s = lsum[it];
        s += __shfl_xor(s, 16, 64);
        s += __shfl_xor(s, 32, 64);
        inv[it] = rcpv(s);
    }

    __syncthreads();                      // all waves done reading vT
    ushort_t* oT_s = vT;                  // reuse as gated-output transpose buffer
#pragma unroll
    for (int ct = 0; ct < 2; ++ct)
#pragma unroll
        for (int it = 0; it < 4; ++it) {
            const int i = w * 64 + it * 16 + l16;
#pragma unroll
            for (int r = 0; r < 4; ++r) {
                const int c = ct * 16 + g * 4 + r;
                const float gate = bflo((uint_t)gT[c * 264 + i]);
                oT_s[c * 264 + i] = f2bf(oT[ct][it][r] * inv[it] * gate);
            }
        }
    __syncthreads();
    // coalesced bf16x2 store to ao[n*256+i][h*32+c]
    ushort_t* aob = ao + (size_t)n * 256 * 256 + h * 32;
#pragma unroll
    for (int iter = 0; iter < 16; ++iter) {
        const int flat = iter * 256 + t;
        const int i = flat >> 4, cp = flat & 15;
        const uint_t lo = oT_s[(2 * cp) * 264 + i];
        const uint_t hi = oT_s[(2 * cp + 1) * 264 + i];
        *(uint_t*)(aob + (size_t)i * 256 + 2 * cp) = lo | (hi << 16);
    }
}

// -------- K4: out = ao @ Wo + bo (MFMA), row-masked --------
__global__ __launch_bounds__(256, 2) void k_out(const ushort_t* __restrict__ ao,
                                                const ushort_t* __restrict__ woT,
                                                const float* __restrict__ bo,
                                                const int* __restrict__ msa_mask,
                                                float* __restrict__ out) {
    const int t = threadIdx.x;
    const int rb = blockIdx.x * 128;
    const int w = t >> 6, l = t & 63;
    const int l16 = l & 15, g = l >> 4;

#pragma unroll
    for (int ch = 0; ch < 2; ++ch) {
        f32x4 acc[2][8];
#pragma unroll
        for (int rt = 0; rt < 2; ++rt)
#pragma unroll
            for (int ct = 0; ct < 8; ++ct) acc[rt][ct] = (f32x4){0.f, 0.f, 0.f, 0.f};
#pragma unroll
        for (int ks = 0; ks < 8; ++ks) {
            bf16x8 a[2], b[8];
#pragma unroll
            for (int rt = 0; rt < 2; ++rt)
                a[rt] = *(const bf16x8*)(ao + (size_t)(rb + w * 32 + rt * 16 + l16) * 256 + ks * 32 + g * 8);
#pragma unroll
            for (int ct = 0; ct < 8; ++ct)
                b[ct] = *(const bf16x8*)(woT + (size_t)(ch * 128 + ct * 16 + l16) * 256 + ks * 32 + g * 8);
#pragma unroll
            for (int rt = 0; rt < 2; ++rt)
#pragma unroll
                for (int ct = 0; ct < 8; ++ct)
                    acc[rt][ct] = mfma16(a[rt], b[ct], acc[rt][ct]);
        }
#pragma unroll
        for (int rt = 0; rt < 2; ++rt)
#pragma unroll
            for (int ct = 0; ct < 8; ++ct) {
                const int c = ch * 128 + ct * 16 + l16;
                const float boc = bo[c];
#pragma unroll
                for (int r = 0; r < 4; ++r) {
                    const int row = rb + w * 32 + rt * 16 + g * 4 + r;
                    const float mk = msa_mask[row] ? 1.f : 0.f;
                    out[(size_t)row * 256 + c] = (acc[rt][ct][r] + boc) * mk;
                }
            }
    }
}

extern "C" void kernel_launch(void* const* d_in, const int* in_sizes, int n_in,
                              void* d_out, int out_size, void* d_ws, size_t ws_size,
                              hipStream_t stream) {
    const float* m       = (const float*)d_in[0];
    const float* z       = (const float*)d_in[1];
    const int* msa_mask  = (const int*)d_in[2];
    const float* ln_m_g  = (const float*)d_in[3];
    const float* ln_m_b  = (const float*)d_in[4];
    const float* ln_z_g  = (const float*)d_in[5];
    const float* ln_z_b  = (const float*)d_in[6];
    const float* Wq      = (const float*)d_in[7];
    const float* Wk      = (const float*)d_in[8];
    const float* Wv      = (const float*)d_in[9];
    const float* Wb      = (const float*)d_in[10];
    const float* Wg      = (const float*)d_in[11];
    const float* bg      = (const float*)d_in[12];
    const float* Wo      = (const float*)d_in[13];
    const float* bo      = (const float*)d_in[14];
    float* out           = (float*)d_out;

    char* ws = (char*)d_ws;
    ushort_t* mn  = (ushort_t*)(ws);                    // 33,554,432 B
    float*    pb  = (float*)(ws + 33554432);            //  2,097,152 B
    ushort_t* ao  = (ushort_t*)(ws + 35651584);         // 33,554,432 B
    ushort_t* wtT = (ushort_t*)(ws + 69206016);         //    524,288 B
    ushort_t* woT = (ushort_t*)(ws + 69730304);         //    131,072 B

    k_prep<<<256, 256, 0, stream>>>(Wq, Wk, Wv, Wg, Wo, wtT, woT);
    k_ln_m<<<16384, 256, 0, stream>>>(m, ln_m_g, ln_m_b, mn);
    k_pair_bias<<<16384, 256, 0, stream>>>(z, ln_z_g, ln_z_b, Wb, pb);
    k_attn<<<2048, 256, 0, stream>>>(mn, wtT, pb, msa_mask, bg, ao);
    k_out<<<512, 256, 0, stream>>>(ao, woT, bo, msa_mask, out);
}

// Round 5
// 297.121 us; speedup vs baseline: 6.5472x; 1.0074x over previous
//
#include <hip/hip_runtime.h>

typedef unsigned short ushort_t;
typedef unsigned int uint_t;
typedef __attribute__((ext_vector_type(8))) short bf16x8;
typedef __attribute__((ext_vector_type(4))) float f32x4;

#define EPSV 1e-5f
#define LOG2E 1.4426950408889634f
#define QSC (0.17677669529663687f * LOG2E)   // (1/sqrt(32)) * log2(e)

__device__ __forceinline__ float u2f(uint_t x) { return __builtin_bit_cast(float, x); }
__device__ __forceinline__ uint_t f2u(float x) { return __builtin_bit_cast(uint_t, x); }
__device__ __forceinline__ float bflo(uint_t u) { return u2f(u << 16); }
__device__ __forceinline__ float bfhi(uint_t u) { return u2f(u & 0xFFFF0000u); }
__device__ __forceinline__ ushort_t f2bf(float f) {
    uint_t x = f2u(f);
    x += 0x7FFFu + ((x >> 16) & 1u);   // RNE
    return (ushort_t)(x >> 16);
}
__device__ __forceinline__ uint_t cvtpk(float lo, float hi) {
    uint_t r;
    asm("v_cvt_pk_bf16_f32 %0, %1, %2" : "=v"(r) : "v"(lo), "v"(hi));
    return r;
}
__device__ __forceinline__ float exp2v(float x) {
    float r;
    asm("v_exp_f32 %0, %1" : "=v"(r) : "v"(x));
    return r;
}
__device__ __forceinline__ float rcpv(float x) {
    float r;
    asm("v_rcp_f32 %0, %1" : "=v"(r) : "v"(x));
    return r;
}
__device__ __forceinline__ f32x4 mfma16(bf16x8 a, bf16x8 b, f32x4 c) {
    return __builtin_amdgcn_mfma_f32_16x16x32_bf16(a, b, c, 0, 0, 0);
}
__device__ __forceinline__ float wsum(float v) {
#pragma unroll
    for (int m = 32; m >= 1; m >>= 1) v += __shfl_xor(v, m, 64);
    return v;
}

// -------- K0: pack transposed bf16 weights: wtT[h][c(128)][k(256)], woT[c][k] --------
__global__ __launch_bounds__(256) void k_prep(const float* __restrict__ Wq, const float* __restrict__ Wk,
                                              const float* __restrict__ Wv, const float* __restrict__ Wg,
                                              const float* __restrict__ Wo,
                                              ushort_t* __restrict__ wtT, ushort_t* __restrict__ woT) {
    const int k = blockIdx.x, t = threadIdx.x;
    const int h = t >> 5, c = t & 31;
    wtT[(size_t)(h * 128 +   0 + c) * 256 + k] = f2bf(Wq[k * 256 + t]);
    wtT[(size_t)(h * 128 +  32 + c) * 256 + k] = f2bf(Wk[k * 256 + t]);
    wtT[(size_t)(h * 128 +  64 + c) * 256 + k] = f2bf(Wv[k * 256 + t]);
    wtT[(size_t)(h * 128 +  96 + c) * 256 + k] = f2bf(Wg[k * 256 + t]);
    woT[(size_t)t * 256 + k] = f2bf(Wo[k * 256 + t]);
}

// -------- K1: LayerNorm(m) -> mn (bf16) --------
__global__ __launch_bounds__(256) void k_ln_m(const float* __restrict__ m,
                                              const float* __restrict__ g,
                                              const float* __restrict__ b,
                                              ushort_t* __restrict__ mn) {
    const int lane = threadIdx.x & 63;
    const int row  = blockIdx.x * 4 + (threadIdx.x >> 6);
    const float4 x = *(const float4*)(m + (size_t)row * 256 + lane * 4);
    const float mu = wsum(x.x + x.y + x.z + x.w) * (1.f / 256.f);
    const float dx = x.x - mu, dy = x.y - mu, dz = x.z - mu, dw = x.w - mu;
    const float var = wsum(dx * dx + dy * dy + dz * dz + dw * dw) * (1.f / 256.f);
    const float rs = rsqrtf(var + EPSV);
    const float4 gg = *(const float4*)(g + lane * 4);
    const float4 bb = *(const float4*)(b + lane * 4);
    ushort4 o;
    o.x = f2bf(dx * rs * gg.x + bb.x);
    o.y = f2bf(dy * rs * gg.y + bb.y);
    o.z = f2bf(dz * rs * gg.z + bb.z);
    o.w = f2bf(dw * rs * gg.w + bb.w);
    *(ushort4*)(mn + (size_t)row * 256 + lane * 4) = o;
}

// -------- K2: LayerNorm(z) @ Wb -> pb[h][i][j] (f32, pre-scaled by log2e) --------
__global__ __launch_bounds__(256) void k_pair_bias(const float* __restrict__ z,
                                                   const float* __restrict__ g,
                                                   const float* __restrict__ b,
                                                   const float* __restrict__ Wb,
                                                   float* __restrict__ pb) {
    const int lane = threadIdx.x & 63;
    const int row  = blockIdx.x * 4 + (threadIdx.x >> 6);
    const float2 x = *(const float2*)(z + (size_t)row * 128 + lane * 2);
    const float mu = wsum(x.x + x.y) * (1.f / 128.f);
    const float d0 = x.x - mu, d1 = x.y - mu;
    const float var = wsum(d0 * d0 + d1 * d1) * (1.f / 128.f);
    const float rs = rsqrtf(var + EPSV);
    const float2 gg = *(const float2*)(g + lane * 2);
    const float2 bb = *(const float2*)(b + lane * 2);
    const float z0 = d0 * rs * gg.x + bb.x;
    const float z1 = d1 * rs * gg.y + bb.y;
    const float4 wa0 = *(const float4*)(Wb + lane * 16 + 0);
    const float4 wa1 = *(const float4*)(Wb + lane * 16 + 4);
    const float4 wb0 = *(const float4*)(Wb + lane * 16 + 8);
    const float4 wb1 = *(const float4*)(Wb + lane * 16 + 12);
    float p[8];
    p[0] = z0 * wa0.x + z1 * wb0.x;
    p[1] = z0 * wa0.y + z1 * wb0.y;
    p[2] = z0 * wa0.z + z1 * wb0.z;
    p[3] = z0 * wa0.w + z1 * wb0.w;
    p[4] = z0 * wa1.x + z1 * wb1.x;
    p[5] = z0 * wa1.y + z1 * wb1.y;
    p[6] = z0 * wa1.z + z1 * wb1.z;
    p[7] = z0 * wa1.w + z1 * wb1.w;
#pragma unroll
    for (int h = 0; h < 8; ++h) p[h] = wsum(p[h]);
    float v = p[0];
#pragma unroll
    for (int h = 1; h < 8; ++h) v = (lane == h) ? p[h] : v;
    if (lane < 8) pb[(size_t)lane * 65536 + row] = v * LOG2E;
}

// -------- K3: MFMA fused QKVG projection + attention (no-max softmax) + gate --------
// blockIdx decode: n = bid & 255, h = bid >> 8 => all 8 heads of one n land on the
// same XCD (XCD = bid % 8 = n % 8), so mn[n] is fetched from HBM once, reused from L2.
__global__ __launch_bounds__(256, 1) void k_attn(const ushort_t* __restrict__ mn,
                                                 const ushort_t* __restrict__ wtT,
                                                 const float* __restrict__ pb,
                                                 const int* __restrict__ msa_mask,
                                                 const float* __restrict__ bg,
                                                 ushort_t* __restrict__ ao) {
    __shared__ ushort_t k_s[256 * 40];   // [j][c], 80B rows
    __shared__ ushort_t qp_s[256 * 40];  // Phase A: q[i][c]; Phase B (after q->regs): P[w][i64][j32] per wave
    __shared__ ushort_t vT[32 * 264];    // [c][j], later reused as gated-output transpose
    __shared__ ushort_t gT[32 * 264];    // [c][i], holds sigmoid gate (bf16)
    __shared__ float maskb[256];

    const int t = threadIdx.x;
    const int n = blockIdx.x & 255, h = blockIdx.x >> 8;
    const int w = t >> 6, l = t & 63;
    const int l16 = l & 15, g = l >> 4;

    maskb[t] = msa_mask[n * 256 + t] ? 0.f : -1.5e9f;
    const float bg0 = bg[h * 32 + l16];
    const float bg1 = bg[h * 32 + 16 + l16];

    const ushort_t* mb = mn + (size_t)n * 65536;
    const ushort_t* wb = wtT + (size_t)h * 128 * 256;

    // ---- Phase A: qkvg[i][c] = mn[i][:] @ W[:,c] via MFMA ----
#pragma unroll
    for (int chalf = 0; chalf < 2; ++chalf) {
        f32x4 acc[4][4];
#pragma unroll
        for (int rt = 0; rt < 4; ++rt)
#pragma unroll
            for (int ct = 0; ct < 4; ++ct) acc[rt][ct] = (f32x4){0.f, 0.f, 0.f, 0.f};

#pragma unroll
        for (int ks = 0; ks < 8; ++ks) {
            bf16x8 a[4], b[4];
#pragma unroll
            for (int rt = 0; rt < 4; ++rt)
                a[rt] = *(const bf16x8*)(mb + (size_t)(w * 64 + rt * 16 + l16) * 256 + ks * 32 + g * 8);
#pragma unroll
            for (int ct = 0; ct < 4; ++ct)
                b[ct] = *(const bf16x8*)(wb + (size_t)(chalf * 64 + ct * 16 + l16) * 256 + ks * 32 + g * 8);
#pragma unroll
            for (int rt = 0; rt < 4; ++rt)
#pragma unroll
                for (int ct = 0; ct < 4; ++ct)
                    acc[rt][ct] = mfma16(a[rt], b[ct], acc[rt][ct]);
        }
        // epilogue: C-frag lane holds [row = g*4+r][col = l16]
#pragma unroll
        for (int ct = 0; ct < 4; ++ct) {
            const int mat = chalf * 2 + (ct >> 1);       // 0 q, 1 k, 2 v, 3 g
            const int cc = (ct & 1) * 16 + l16;
#pragma unroll
            for (int rt = 0; rt < 4; ++rt) {
                const int i0 = w * 64 + rt * 16 + g * 4;
                const f32x4 v = acc[rt][ct];
                if (mat == 0) {          // q: fold SCALE*log2e
#pragma unroll
                    for (int r = 0; r < 4; ++r) qp_s[(i0 + r) * 40 + cc] = f2bf(v[r] * QSC);
                } else if (mat == 1) {   // k
#pragma unroll
                    for (int r = 0; r < 4; ++r) k_s[(i0 + r) * 40 + cc] = f2bf(v[r]);
                } else if (mat == 2) {   // v -> transposed
                    const uint_t lo = cvtpk(v[0], v[1]);
                    const uint_t hi = cvtpk(v[2], v[3]);
                    *(uint2*)(vT + cc * 264 + i0) = make_uint2(lo, hi);
                } else {                 // g -> sigmoid gate, transposed
                    const float bgc = (ct & 1) ? bg1 : bg0;
                    float gt[4];
#pragma unroll
                    for (int r = 0; r < 4; ++r)
                        gt[r] = rcpv(1.f + exp2v(-(v[r] + bgc) * LOG2E));
                    const uint_t lo = cvtpk(gt[0], gt[1]);
                    const uint_t hi = cvtpk(gt[2], gt[3]);
                    *(uint2*)(gT + cc * 264 + i0) = make_uint2(lo, hi);
                }
            }
        }
    }
    __syncthreads();

    // ---- Phase B: attention. Wave w owns rows i in [w*64, w*64+64). ----
    // Hoist q fragments to registers, then reuse qp_s rows [w*64, w*64+64) as the
    // wave-private P buffer (no barrier needed: same-wave producer/consumer).
    bf16x8 bq[4];
#pragma unroll
    for (int it = 0; it < 4; ++it)
        bq[it] = *(const bf16x8*)&qp_s[(w * 64 + it * 16 + l16) * 40 + g * 8];
    ushort_t* p_w = qp_s + w * 64 * 40;

    const float* pbh = pb + (size_t)h * 65536;
    f32x4 oT[2][4];
#pragma unroll
    for (int ct = 0; ct < 2; ++ct)
#pragma unroll
        for (int it = 0; it < 4; ++it) oT[ct][it] = (f32x4){0.f, 0.f, 0.f, 0.f};
    float lsum[4] = {0.f, 0.f, 0.f, 0.f};

    for (int jc = 0; jc < 8; ++jc) {
        // issue pair-bias loads early (L2 latency hides under S-MFMAs)
        f32x4 pb0[4], pb1[4];
#pragma unroll
        for (int it = 0; it < 4; ++it) {
            const int i = w * 64 + it * 16 + l16;
            pb0[it] = *(const f32x4*)(pbh + (size_t)i * 256 + jc * 32 + g * 4);
            pb1[it] = *(const f32x4*)(pbh + (size_t)i * 256 + jc * 32 + 16 + g * 4);
        }
        bf16x8 ak[2], av[2];
#pragma unroll
        for (int jt = 0; jt < 2; ++jt)
            ak[jt] = *(const bf16x8*)&k_s[(jc * 32 + jt * 16 + l16) * 40 + g * 8];
#pragma unroll
        for (int ct = 0; ct < 2; ++ct)
            av[ct] = *(const bf16x8*)&vT[(ct * 16 + l16) * 264 + jc * 32 + g * 8];

        // S^T = mfma(K, Q): lane holds S[j = jc*32 + jt*16 + g*4 + r][i = it*16 + l16]
        f32x4 st[2][4];
#pragma unroll
        for (int jt = 0; jt < 2; ++jt)
#pragma unroll
            for (int it = 0; it < 4; ++it)
                st[jt][it] = mfma16(ak[jt], bq[it], (f32x4){0.f, 0.f, 0.f, 0.f});

        const f32x4 mk0 = *(const f32x4*)&maskb[jc * 32 + g * 4];
        const f32x4 mk1 = *(const f32x4*)&maskb[jc * 32 + 16 + g * 4];

        // softmax numerator (no max subtraction; logits are O(1), masked -> exp2(-1.5e9)=0)
#pragma unroll
        for (int it = 0; it < 4; ++it) {
            float p0[4], p1[4];
#pragma unroll
            for (int r = 0; r < 4; ++r) {
                p0[r] = exp2v(st[0][it][r] + pb0[it][r] + mk0[r]);
                p1[r] = exp2v(st[1][it][r] + pb1[it][r] + mk1[r]);
            }
#pragma unroll
            for (int r = 0; r < 4; ++r) lsum[it] += p0[r] + p1[r];
            ushort_t* base = p_w + (it * 16 + l16) * 40;
            *(uint2*)(base + g * 4)      = make_uint2(cvtpk(p0[0], p0[1]), cvtpk(p0[2], p0[3]));
            *(uint2*)(base + 16 + g * 4) = make_uint2(cvtpk(p1[0], p1[1]), cvtpk(p1[2], p1[3]));
        }
        // PV: O^T += mfma(V^T, P)
#pragma unroll
        for (int it = 0; it < 4; ++it) {
            const bf16x8 bp = *(const bf16x8*)&p_w[(it * 16 + l16) * 40 + g * 8];
            oT[0][it] = mfma16(av[0], bp, oT[0][it]);
            oT[1][it] = mfma16(av[1], bp, oT[1][it]);
        }
    }

    float inv[4];
#pragma unroll
    for (int it = 0; it < 4; ++it) {
        float s = lsum[it];
        s += __shfl_xor(s, 16, 64);
        s += __shfl_xor(s, 32, 64);
        inv[it] = rcpv(s);
    }

    __syncthreads();                      // all waves done reading vT
    ushort_t* oT_s = vT;                  // reuse as gated-output transpose buffer
#pragma unroll
    for (int ct = 0; ct < 2; ++ct)
#pragma unroll
        for (int it = 0; it < 4; ++it) {
            const int i = w * 64 + it * 16 + l16;
#pragma unroll
            for (int r = 0; r < 4; ++r) {
                const int c = ct * 16 + g * 4 + r;
                const float gate = bflo((uint_t)gT[c * 264 + i]);
                oT_s[c * 264 + i] = f2bf(oT[ct][it][r] * inv[it] * gate);
            }
        }
    __syncthreads();
    // coalesced bf16x2 store to ao[n*256+i][h*32+c]
    ushort_t* aob = ao + (size_t)n * 256 * 256 + h * 32;
#pragma unroll
    for (int iter = 0; iter < 16; ++iter) {
        const int flat = iter * 256 + t;
        const int i = flat >> 4, cp = flat & 15;
        const uint_t lo = oT_s[(2 * cp) * 264 + i];
        const uint_t hi = oT_s[(2 * cp + 1) * 264 + i];
        *(uint_t*)(aob + (size_t)i * 256 + 2 * cp) = lo | (hi << 16);
    }
}

// -------- K4: out = ao @ Wo + bo (MFMA), row-masked --------
__global__ __launch_bounds__(256, 2) void k_out(const ushort_t* __restrict__ ao,
                                                const ushort_t* __restrict__ woT,
                                                const float* __restrict__ bo,
                                                const int* __restrict__ msa_mask,
                                                float* __restrict__ out) {
    const int t = threadIdx.x;
    const int rb = blockIdx.x * 128;
    const int w = t >> 6, l = t & 63;
    const int l16 = l & 15, g = l >> 4;

#pragma unroll
    for (int ch = 0; ch < 2; ++ch) {
        f32x4 acc[2][8];
#pragma unroll
        for (int rt = 0; rt < 2; ++rt)
#pragma unroll
            for (int ct = 0; ct < 8; ++ct) acc[rt][ct] = (f32x4){0.f, 0.f, 0.f, 0.f};
#pragma unroll
        for (int ks = 0; ks < 8; ++ks) {
            bf16x8 a[2], b[8];
#pragma unroll
            for (int rt = 0; rt < 2; ++rt)
                a[rt] = *(const bf16x8*)(ao + (size_t)(rb + w * 32 + rt * 16 + l16) * 256 + ks * 32 + g * 8);
#pragma unroll
            for (int ct = 0; ct < 8; ++ct)
                b[ct] = *(const bf16x8*)(woT + (size_t)(ch * 128 + ct * 16 + l16) * 256 + ks * 32 + g * 8);
#pragma unroll
            for (int rt = 0; rt < 2; ++rt)
#pragma unroll
                for (int ct = 0; ct < 8; ++ct)
                    acc[rt][ct] = mfma16(a[rt], b[ct], acc[rt][ct]);
        }
#pragma unroll
        for (int rt = 0; rt < 2; ++rt)
#pragma unroll
            for (int ct = 0; ct < 8; ++ct) {
                const int c = ch * 128 + ct * 16 + l16;
                const float boc = bo[c];
#pragma unroll
                for (int r = 0; r < 4; ++r) {
                    const int row = rb + w * 32 + rt * 16 + g * 4 + r;
                    const float mk = msa_mask[row] ? 1.f : 0.f;
                    out[(size_t)row * 256 + c] = (acc[rt][ct][r] + boc) * mk;
                }
            }
    }
}

extern "C" void kernel_launch(void* const* d_in, const int* in_sizes, int n_in,
                              void* d_out, int out_size, void* d_ws, size_t ws_size,
                              hipStream_t stream) {
    const float* m       = (const float*)d_in[0];
    const float* z       = (const float*)d_in[1];
    const int* msa_mask  = (const int*)d_in[2];
    const float* ln_m_g  = (const float*)d_in[3];
    const float* ln_m_b  = (const float*)d_in[4];
    const float* ln_z_g  = (const float*)d_in[5];
    const float* ln_z_b  = (const float*)d_in[6];
    const float* Wq      = (const float*)d_in[7];
    const float* Wk      = (const float*)d_in[8];
    const float* Wv      = (const float*)d_in[9];
    const float* Wb      = (const float*)d_in[10];
    const float* Wg      = (const float*)d_in[11];
    const float* bg      = (const float*)d_in[12];
    const float* Wo      = (const float*)d_in[13];
    const float* bo      = (const float*)d_in[14];
    float* out           = (float*)d_out;

    char* ws = (char*)d_ws;
    ushort_t* mn  = (ushort_t*)(ws);                    // 33,554,432 B
    float*    pb  = (float*)(ws + 33554432);            //  2,097,152 B
    ushort_t* ao  = (ushort_t*)(ws + 35651584);         // 33,554,432 B
    ushort_t* wtT = (ushort_t*)(ws + 69206016);         //    524,288 B
    ushort_t* woT = (ushort_t*)(ws + 69730304);         //    131,072 B

    k_prep<<<256, 256, 0, stream>>>(Wq, Wk, Wv, Wg, Wo, wtT, woT);
    k_ln_m<<<16384, 256, 0, stream>>>(m, ln_m_g, ln_m_b, mn);
    k_pair_bias<<<16384, 256, 0, stream>>>(z, ln_z_g, ln_z_b, Wb, pb);
    k_attn<<<2048, 256, 0, stream>>>(mn, wtT, pb, msa_mask, bg, ao);
    k_out<<<512, 256, 0, stream>>>(ao, woT, bo, msa_mask, out);
}